// Round 2
// baseline (151.685 us; speedup 1.0000x reference)
//
#include <hip/hip_runtime.h>
#include <hip/hip_bf16.h>

typedef __attribute__((ext_vector_type(8))) __bf16 bf16x8;
typedef __attribute__((ext_vector_type(4))) float f32x4;

#define N_NODES 50000
#define N_EDGES 800000
#define N_TILES (N_EDGES / 16)   // 50000 16-edge tiles (800000 % 16 == 0)
#define WAVES 4
#define TPW 8                    // tiles per wave per block
#define TILES_PER_BLOCK (WAVES * TPW)   // 32 -> 512 edges/block

__global__ __launch_bounds__(256) void edge_mlp_kernel(
    const float* __restrict__ x_s, const float* __restrict__ x_t,
    const int* __restrict__ edge_index, const float* __restrict__ edge_attr,
    const float* __restrict__ u, const int* __restrict__ batch_e,
    const float* __restrict__ W1, const float* __restrict__ b1,
    const float* __restrict__ W2, const float* __restrict__ b2,
    float* __restrict__ out)
{
    // W1t rows padded to 264 elems (528 B = 132 dwords, 132 % 32 = 4 -> only
    // 2-way bank aliasing on the 16-row fragment reads, which is free).
    __shared__ __align__(16) __bf16 sW1t[64][264];   // [n][k]  33792 B
    __shared__ __align__(16) __bf16 sW2t[64][72];    // [n][k]   9216 B
    __shared__ __align__(16) __bf16 sH1[WAVES][16][72]; //        9216 B
    __shared__ float sB1[64];
    __shared__ float sB2[64];

    const int t = threadIdx.x;

    // ---- stage weights (bf16, transposed so B-fragments are contiguous) ----
    for (int idx = t; idx < 256 * 64; idx += 256) {
        int k = idx >> 6, n = idx & 63;
        sW1t[n][k] = (__bf16)W1[idx];
    }
    for (int idx = t; idx < 64 * 64; idx += 256) {
        int k = idx >> 6, n = idx & 63;
        sW2t[n][k] = (__bf16)W2[idx];
    }
    if (t < 64) { sB1[t] = b1[t]; sB2[t] = b2[t]; }
    __syncthreads();

    const int wave = t >> 6;
    const int lane = t & 63;
    const int l15  = lane & 15;   // A row / B col within 16
    const int lk   = lane >> 4;   // k-group 0..3

    for (int i = 0; i < TPW; ++i) {
        const int tile = (blockIdx.x * WAVES + wave) * TPW + i;
        if (tile >= N_TILES) break;

        const int e   = tile * 16 + l15;
        const int src = edge_index[e];
        const int tgt = edge_index[N_EDGES + e];
        const int bg  = batch_e[e];

        const float* seg0 = x_s + (long long)src * 64;
        const float* seg1 = x_t + (long long)tgt * 64;
        const float* seg2 = edge_attr + (long long)e * 64;
        const float* seg3 = u + (long long)bg * 64;

        f32x4 acc[4] = {{0,0,0,0},{0,0,0,0},{0,0,0,0},{0,0,0,0}};

        // ---- GEMM1: [16 x 256] x [256 x 64], K in 8 steps of 32 ----
        #pragma unroll
        for (int kk = 0; kk < 8; ++kk) {
            const int k0 = kk * 32 + lk * 8;       // this lane's k-chunk
            const float* p =
                (k0 < 64)  ? (seg0 + k0) :
                (k0 < 128) ? (seg1 + (k0 - 64)) :
                (k0 < 192) ? (seg2 + (k0 - 128)) :
                             (seg3 + (k0 - 192));
            float4 f0 = *(const float4*)p;
            float4 f1 = *(const float4*)(p + 4);
            bf16x8 a;
            a[0] = (__bf16)f0.x; a[1] = (__bf16)f0.y;
            a[2] = (__bf16)f0.z; a[3] = (__bf16)f0.w;
            a[4] = (__bf16)f1.x; a[5] = (__bf16)f1.y;
            a[6] = (__bf16)f1.z; a[7] = (__bf16)f1.w;
            #pragma unroll
            for (int nf = 0; nf < 4; ++nf) {
                bf16x8 b = *(const bf16x8*)&sW1t[nf * 16 + l15][k0];
                acc[nf] = __builtin_amdgcn_mfma_f32_16x16x32_bf16(a, b, acc[nf], 0, 0, 0);
            }
        }

        // ---- bias + LeakyReLU(0.1) -> bf16 -> per-wave LDS tile ----
        #pragma unroll
        for (int nf = 0; nf < 4; ++nf) {
            const float bv = sB1[nf * 16 + l15];
            #pragma unroll
            for (int r = 0; r < 4; ++r) {
                float v = acc[nf][r] + bv;
                v = (v >= 0.f) ? v : 0.1f * v;
                // C layout: row = lk*4 + r, col = l15 (m89-verified)
                sH1[wave][lk * 4 + r][nf * 16 + l15] = (__bf16)v;
            }
        }
        asm volatile("s_waitcnt lgkmcnt(0)" ::: "memory");
        __builtin_amdgcn_sched_barrier(0);

        // ---- GEMM2: [16 x 64] x [64 x 64], K in 2 steps of 32 ----
        f32x4 acc2[4] = {{0,0,0,0},{0,0,0,0},{0,0,0,0},{0,0,0,0}};
        #pragma unroll
        for (int kk = 0; kk < 2; ++kk) {
            const int k0 = kk * 32 + lk * 8;
            bf16x8 a2 = *(const bf16x8*)&sH1[wave][l15][k0];
            #pragma unroll
            for (int nf = 0; nf < 4; ++nf) {
                bf16x8 b = *(const bf16x8*)&sW2t[nf * 16 + l15][k0];
                acc2[nf] = __builtin_amdgcn_mfma_f32_16x16x32_bf16(a2, b, acc2[nf], 0, 0, 0);
            }
        }

        // ---- + b2, store fp32 ----
        float* orow = out + (long long)tile * 16 * 64;
        #pragma unroll
        for (int nf = 0; nf < 4; ++nf) {
            const float bv = sB2[nf * 16 + l15];
            #pragma unroll
            for (int r = 0; r < 4; ++r) {
                orow[(lk * 4 + r) * 64 + nf * 16 + l15] = acc2[nf][r] + bv;
            }
        }
    }
}

extern "C" void kernel_launch(void* const* d_in, const int* in_sizes, int n_in,
                              void* d_out, int out_size, void* d_ws, size_t ws_size,
                              hipStream_t stream) {
    const float* x_s       = (const float*)d_in[0];
    const float* x_t       = (const float*)d_in[1];
    const int*   edge_index= (const int*)d_in[2];   // harness: integer -> int32
    const float* edge_attr = (const float*)d_in[3];
    const float* u         = (const float*)d_in[4];
    const int*   batch_e   = (const int*)d_in[5];
    const float* W1        = (const float*)d_in[6];
    const float* b1        = (const float*)d_in[7];
    const float* W2        = (const float*)d_in[8];
    const float* b2        = (const float*)d_in[9];
    float*       out       = (float*)d_out;

    const int nblocks = (N_TILES + TILES_PER_BLOCK - 1) / TILES_PER_BLOCK; // 1563
    edge_mlp_kernel<<<nblocks, 256, 0, stream>>>(
        x_s, x_t, edge_index, edge_attr, u, batch_e, W1, b1, W2, b2, out);
}